// Round 8
// baseline (635.541 us; speedup 1.0000x reference)
//
#include <hip/hip_runtime.h>
#include <hip/hip_bf16.h>
#include <cstddef>
#include <cstdint>

#define B_  32
#define S_  50
#define L_  20
#define R_  16
#define D_  100
#define V_  50000
#define T_  320       // L_*R_
#define RD_ 1600      // R_*D_
#define BS_ 1600      // B_*S_

// ---------------- Phase A: x[bs][j] = sum_l emb0[stories[bs][r*20+l]][d] * in_mult[r*20+l][d]
__global__ __launch_bounds__(512) void x_kernel(
    const int* __restrict__ stories, const float* __restrict__ emb,
    const float* __restrict__ in_mult, float* __restrict__ x)
{
  __shared__ int toks[T_];
  const int bs = blockIdx.x, tid = threadIdx.x;
  const int* st = stories + (size_t)bs * T_;
  if (tid < T_) toks[tid] = st[tid];
  __syncthreads();
  if (tid < 400) {
    const int j4 = tid * 4;
    const int r  = j4 / D_;
    const int d4 = j4 - r * D_;
    float4 acc = make_float4(0.f, 0.f, 0.f, 0.f);
    #pragma unroll
    for (int l = 0; l < 20; ++l) {
      const int t = r * 20 + l;
      const int tok = toks[t];
      if (tok != 0) {
        float4 e = *(const float4*)&emb[(size_t)tok * D_ + d4];
        float4 m = *(const float4*)&in_mult[(size_t)t * D_ + d4];
        acc.x += e.x * m.x; acc.y += e.y * m.y;
        acc.z += e.z * m.z; acc.w += e.w * m.w;
      }
    }
    *(float4*)&x[(size_t)bs * RD_ + j4] = acc;
  }
}

// ---------------- v_keys[j] = sum_k keys_flat[k] * Vw[j][k]  (one wave per j)
__global__ __launch_bounds__(256) void vkeys_kernel(
    const float* __restrict__ keys, const float* __restrict__ Vw, float* __restrict__ vk)
{
  int wave = threadIdx.x >> 6, lane = threadIdx.x & 63;
  int j = blockIdx.x * 4 + wave;
  float acc = 0.f;
  for (int k = lane; k < RD_; k += 64)
    acc += keys[k] * Vw[(size_t)j * RD_ + k];
  #pragma unroll
  for (int off = 32; off > 0; off >>= 1) acc += __shfl_down(acc, off);
  if (lane == 0) vk[j] = acc;
}

// ---------------- u0[j] = sum_k U[j][k] * init_state[k]  (one wave per j)
__global__ __launch_bounds__(256) void u0_kernel(
    const float* __restrict__ U, const float* __restrict__ init_state,
    float* __restrict__ u0)
{
  int wave = threadIdx.x >> 6, lane = threadIdx.x & 63;
  int j = blockIdx.x * 4 + wave;
  const float* Ur = U + (size_t)j * D_;
  float acc = Ur[lane] * init_state[lane];
  if (lane < 36) acc += Ur[64 + lane] * init_state[64 + lane];
  #pragma unroll
  for (int off = 32; off > 0; off >>= 1) acc += __shfl_down(acc, off);
  if (lane == 0) u0[j] = acc;
}

// ---------------- sign table from U directly:
// table[g][p][j] = sum_{i<4} (±)U[j][4g+i], p bit i => minus
__global__ __launch_bounds__(256) void table_kernel(
    const float* __restrict__ U, float* __restrict__ table)
{
  const int g = blockIdx.x >> 4, p = blockIdx.x & 15;
  const float s0 = (p & 1) ? -1.f : 1.f;
  const float s1 = (p & 2) ? -1.f : 1.f;
  const float s2 = (p & 4) ? -1.f : 1.f;
  const float s3 = (p & 8) ? -1.f : 1.f;
  for (int f = threadIdx.x; f < 400; f += 256) {
    const int j4 = f * 4;
    float t[4];
    #pragma unroll
    for (int jj = 0; jj < 4; ++jj) {
      float4 uv = *(const float4*)&U[(size_t)(j4 + jj) * D_ + 4 * g];
      t[jj] = s0 * uv.x + s1 * uv.y + s2 * uv.z + s3 * uv.w;
    }
    *(float4*)&table[((size_t)(g * 16 + p)) * RD_ + j4] =
        make_float4(t[0], t[1], t[2], t[3]);
  }
}

// ---------------- C[m][n] = sum_k A[m][k]*B[n][k]  (NT fp32, 128x128 tile, 256 thr,
// TM=TN=8 split 4+64 (conflict-free LDS reads), BK=16, LDS double-buffered)
__global__ __launch_bounds__(256, 1) void gemm_nt_kernel(
    const float* __restrict__ A, const float* __restrict__ B, float* __restrict__ C)
{
  __shared__ __align__(16) float As[2][16][132];
  __shared__ __align__(16) float Bs[2][16][132];
  const int tid = threadIdx.x;
  const int bm = blockIdx.y * 128, bn = blockIdx.x * 128;
  const int tx = tid & 15, ty = tid >> 4;
  const int row = tid >> 1, c = tid & 1;   // staging: row 0..127, k-half c*8

  int ga = bm + row; if (ga > RD_ - 1) ga = RD_ - 1;
  int gb = bn + row; if (gb > RD_ - 1) gb = RD_ - 1;
  const float* Ar = &A[(size_t)ga * RD_ + c * 8];
  const float* Br = &B[(size_t)gb * RD_ + c * 8];

  float4 sa0 = *(const float4*)Ar, sa1 = *(const float4*)(Ar + 4);
  float4 sb0 = *(const float4*)Br, sb1 = *(const float4*)(Br + 4);
  #pragma unroll
  for (int e = 0; e < 4; ++e) {
    As[0][c*8 + e][row]     = (&sa0.x)[e];
    As[0][c*8 + 4 + e][row] = (&sa1.x)[e];
    Bs[0][c*8 + e][row]     = (&sb0.x)[e];
    Bs[0][c*8 + 4 + e][row] = (&sb1.x)[e];
  }
  __syncthreads();

  float acc[2][2][4][4] = {};
  for (int t = 0; t < 100; ++t) {
    const int cur = t & 1;
    if (t < 99) {
      const float* An = Ar + (t + 1) * 16;
      const float* Bn = Br + (t + 1) * 16;
      sa0 = *(const float4*)An; sa1 = *(const float4*)(An + 4);
      sb0 = *(const float4*)Bn; sb1 = *(const float4*)(Bn + 4);
    }
    #pragma unroll
    for (int k = 0; k < 16; ++k) {
      float4 a0 = *(const float4*)&As[cur][k][ty * 4];
      float4 a1 = *(const float4*)&As[cur][k][ty * 4 + 64];
      float4 b0 = *(const float4*)&Bs[cur][k][tx * 4];
      float4 b1 = *(const float4*)&Bs[cur][k][tx * 4 + 64];
      float am[2][4] = {{a0.x,a0.y,a0.z,a0.w},{a1.x,a1.y,a1.z,a1.w}};
      float bv[2][4] = {{b0.x,b0.y,b0.z,b0.w},{b1.x,b1.y,b1.z,b1.w}};
      #pragma unroll
      for (int qm = 0; qm < 2; ++qm)
        #pragma unroll
        for (int qn = 0; qn < 2; ++qn)
          #pragma unroll
          for (int i = 0; i < 4; ++i)
            #pragma unroll
            for (int j = 0; j < 4; ++j)
              acc[qm][qn][i][j] += am[qm][i] * bv[qn][j];
    }
    if (t < 99) {
      const int nxt = cur ^ 1;
      #pragma unroll
      for (int e = 0; e < 4; ++e) {
        As[nxt][c*8 + e][row]     = (&sa0.x)[e];
        As[nxt][c*8 + 4 + e][row] = (&sa1.x)[e];
        Bs[nxt][c*8 + e][row]     = (&sb0.x)[e];
        Bs[nxt][c*8 + 4 + e][row] = (&sb1.x)[e];
      }
    }
    __syncthreads();
  }
  #pragma unroll
  for (int qm = 0; qm < 2; ++qm)
    #pragma unroll
    for (int i = 0; i < 4; ++i) {
      const int gr = bm + qm * 64 + ty * 4 + i;
      if (gr < RD_) {
        #pragma unroll
        for (int qn = 0; qn < 2; ++qn) {
          const int gc = bn + qn * 64 + tx * 4;
          if (gc < RD_)
            *(float4*)&C[(size_t)gr * RD_ + gc] =
                make_float4(acc[qm][qn][i][0], acc[qm][qn][i][1],
                            acc[qm][qn][i][2], acc[qm][qn][i][3]);
        }
      }
    }
}

// ---------------- scan: one block per b. Step 0 via precomputed u0,
// steps>=1 via sign table. Staggered 5-deep register prefetch of x/Wall rows.
__global__ __launch_bounds__(512, 2) void scan_kernel(
    const float* __restrict__ x,       // [BS_][RD_]
    const float* __restrict__ Wall,    // [BS_][RD_]
    const float* __restrict__ table,   // [25*16][RD_]
    const float* __restrict__ u0,      // [RD_]
    const float* __restrict__ vkeys,   // [RD_]
    const float* __restrict__ keys,    // [RD_]
    const float* __restrict__ init_state, // [D_]
    const float* __restrict__ alpha_in_p,
    float* __restrict__ state_out)     // [B_][D_]
{
  const int b = blockIdx.x, tid = threadIdx.x;
  __shared__ __align__(16) float s_state[D_];
  __shared__ __align__(16) float s_c[RD_];
  __shared__ unsigned long long s_mask[2];
  const float alpha = alpha_in_p[0];
  const bool active = (tid < 400);
  const int j4 = tid * 4;
  const int d4 = (j4 % D_);
  float4 kk = make_float4(0.f,0.f,0.f,0.f), vv = kk;
  const float* xb = x    + (size_t)b * S_ * RD_;
  const float* wb = Wall + (size_t)b * S_ * RD_;
  float4 bx[5], bw[5];
  #pragma unroll
  for (int i = 0; i < 5; ++i) { bx[i] = make_float4(0.f,0.f,0.f,0.f); bw[i] = bx[i]; }
  if (active) {
    kk = *(const float4*)&keys[j4];
    vv = *(const float4*)&vkeys[j4];
    #pragma unroll
    for (int i = 0; i < 5; ++i) {          // preload steps 0..4
      bx[i] = *(const float4*)&xb[(size_t)i * RD_ + j4];
      bw[i] = *(const float4*)&wb[(size_t)i * RD_ + j4];
    }
  }
  if (tid < D_) s_state[tid] = init_state[tid];
  __syncthreads();

  for (int sg = 0; sg < S_; sg += 5) {
    #pragma unroll
    for (int i = 0; i < 5; ++i) {
      const int s = sg + i;
      if (active) {
        const float4 sent = bx[i], w = bw[i];
        if (s + 5 < S_) {                  // issue prefetch for step s+5 now
          bx[i] = *(const float4*)&xb[(size_t)(s + 5) * RD_ + j4];
          bw[i] = *(const float4*)&wb[(size_t)(s + 5) * RD_ + j4];
        }
        float4 u;
        if (s == 0) {
          u = *(const float4*)&u0[j4];
        } else {
          u = make_float4(0.f,0.f,0.f,0.f);
          const unsigned long long m0 = s_mask[0];
          const unsigned long long m1 = s_mask[1];
          #pragma unroll
          for (int g = 0; g < 25; ++g) {
            const unsigned idx = (g < 16)
                ? (unsigned)((m0 >> (4 * g)) & 15ull)
                : (unsigned)((m1 >> (4 * g - 64)) & 15ull);
            float4 tv = *(const float4*)&table[((size_t)(g * 16) + idx) * RD_ + j4];
            u.x += tv.x; u.y += tv.y; u.z += tv.z; u.w += tv.w;
          }
        }
        float4 sd = *(const float4*)&s_state[d4];
        float zx = sent.x * sd.x + sent.x * kk.x;
        float zy = sent.y * sd.y + sent.y * kk.y;
        float zz = sent.z * sd.z + sent.z * kk.z;
        float zw = sent.w * sd.w + sent.w * kk.w;
        float gx = 1.0f / (1.0f + expf(-zx));
        float gy = 1.0f / (1.0f + expf(-zy));
        float gz = 1.0f / (1.0f + expf(-zz));
        float gw = 1.0f / (1.0f + expf(-zw));
        float cx = u.x + vv.x + w.x; cx = cx >= 0.f ? cx : alpha * cx;
        float cy = u.y + vv.y + w.y; cy = cy >= 0.f ? cy : alpha * cy;
        float cz = u.z + vv.z + w.z; cz = cz >= 0.f ? cz : alpha * cz;
        float cw = u.w + vv.w + w.w; cw = cw >= 0.f ? cw : alpha * cw;
        float4 cc;
        cc.x = (gx == 0.5f) ? 0.f : cx * gx;
        cc.y = (gy == 0.5f) ? 0.f : cy * gy;
        cc.z = (gz == 0.5f) ? 0.f : cz * gz;
        cc.w = (gw == 0.5f) ? 0.f : cw * gw;
        *(float4*)&s_c[j4] = cc;
      }
      __syncthreads();
      if (tid < D_) {
        float csum = 0.f;
        #pragma unroll
        for (int r = 0; r < R_; ++r) csum += s_c[r * D_ + tid];
        float v = s_state[tid] + csum;
        v = v / sqrtf(v * v);   // faithful: torch.norm over singleton dim -> sign
        s_state[tid] = v;
        unsigned long long mask = __ballot(v < 0.f);
        if ((tid & 63) == 0) s_mask[tid >> 6] = mask;
      }
      __syncthreads();
    }
  }
  if (tid < D_) state_out[(size_t)b * D_ + tid] = s_state[tid];
}

// ---------------- h[b][d] = prelu( q[b][d] + sum_k state[b][k]*Hw[d][k], alpha_q )
__global__ void head_kernel(
    const int* __restrict__ queries, const float* __restrict__ emb,
    const float* __restrict__ q_mult, const float* __restrict__ state_g,
    const float* __restrict__ Hw, const float* __restrict__ alpha_q_p,
    float* __restrict__ h_g)
{
  int b = blockIdx.x, d = threadIdx.x;
  if (d >= D_) return;
  float q = 0.f;
  #pragma unroll
  for (int l = 0; l < L_; ++l) {
    int tok = queries[b * L_ + l];
    if (tok != 0) q += emb[(size_t)tok * D_ + d] * q_mult[l * D_ + d];
  }
  float acc = 0.f;
  const float* st = state_g + (size_t)b * D_;
  #pragma unroll 4
  for (int k = 0; k < D_; ++k) acc += st[k] * Hw[(size_t)d * D_ + k];
  float h = q + acc;
  float alpha = alpha_q_p[0];
  h = h >= 0.f ? h : alpha * h;
  h_g[(size_t)b * D_ + d] = h;
}

// ---------------- out[b][v] = sum_k h[b][k] * Rw[v][k]   (v-tile=32 staged in LDS)
__global__ __launch_bounds__(256) void out_kernel(
    const float* __restrict__ h_g, const float* __restrict__ Rw, float* __restrict__ out)
{
  __shared__ __align__(16) float sh[B_ * D_];    // 3200
  __shared__ __align__(16) float sr[32 * D_];    // 3200
  int tid = threadIdx.x;
  int v0 = blockIdx.x * 32;
  for (int i = tid; i < B_ * D_; i += 256) sh[i] = h_g[i];
  int nrows = V_ - v0; if (nrows > 32) nrows = 32;
  for (int i = tid; i < nrows * D_; i += 256) sr[i] = Rw[(size_t)v0 * D_ + i];
  __syncthreads();
  const float4* sh4 = (const float4*)sh;
  const float4* sr4 = (const float4*)sr;
  int tv = (tid & 15) * 2;
  int tb = (tid >> 4) * 2;
  float a00 = 0.f, a01 = 0.f, a10 = 0.f, a11 = 0.f;
  #pragma unroll
  for (int kc = 0; kc < 25; ++kc) {
    float4 h0 = sh4[tb * 25 + kc];
    float4 h1 = sh4[(tb + 1) * 25 + kc];
    float4 r0 = sr4[tv * 25 + kc];
    float4 r1 = sr4[(tv + 1) * 25 + kc];
    a00 += h0.x*r0.x + h0.y*r0.y + h0.z*r0.z + h0.w*r0.w;
    a01 += h0.x*r1.x + h0.y*r1.y + h0.z*r1.z + h0.w*r1.w;
    a10 += h1.x*r0.x + h1.y*r0.y + h1.z*r0.z + h1.w*r0.w;
    a11 += h1.x*r1.x + h1.y*r1.y + h1.z*r1.z + h1.w*r1.w;
  }
  if (tv < nrows) {
    out[(size_t)tb * V_ + v0 + tv] = a00;
    out[(size_t)(tb + 1) * V_ + v0 + tv] = a10;
  }
  if (tv + 1 < nrows) {
    out[(size_t)tb * V_ + v0 + tv + 1] = a01;
    out[(size_t)(tb + 1) * V_ + v0 + tv + 1] = a11;
  }
}

extern "C" void kernel_launch(void* const* d_in, const int* in_sizes, int n_in,
                              void* d_out, int out_size, void* d_ws, size_t ws_size,
                              hipStream_t stream) {
  const int*   stories    = (const int*)  d_in[0];
  const int*   queries    = (const int*)  d_in[1];
  const float* emb        = (const float*)d_in[2];
  const float* in_mult    = (const float*)d_in[3];
  const float* q_mult     = (const float*)d_in[4];
  const float* keys       = (const float*)d_in[5];
  const float* init_state = (const float*)d_in[6];
  const float* U          = (const float*)d_in[7];
  const float* Vw         = (const float*)d_in[8];
  const float* Ww         = (const float*)d_in[9];
  const float* Hw         = (const float*)d_in[10];
  const float* Rw         = (const float*)d_in[11];
  const float* alpha_in   = (const float*)d_in[12];
  const float* alpha_q    = (const float*)d_in[13];
  float* out = (float*)d_out;

  char* ws = (char*)d_ws;
  float* x     = (float*)(ws);               // 10,240,000 B
  float* Wall  = (float*)(ws + 10240000);    // 10,240,000 B
  float* table = (float*)(ws + 20480000);    //  2,560,000 B
  float* vk    = (float*)(ws + 23040000);    //      6,400 B
  float* u0    = (float*)(ws + 23046400);    //      6,400 B
  float* state = (float*)(ws + 23052800);    //     12,800 B
  float* hbuf  = (float*)(ws + 23065600);    //     12,800 B
  // total 23,078,400 B

  x_kernel<<<BS_, 512, 0, stream>>>(stories, emb, in_mult, x);
  vkeys_kernel<<<RD_ / 4, 256, 0, stream>>>(keys, Vw, vk);
  u0_kernel<<<RD_ / 4, 256, 0, stream>>>(U, init_state, u0);
  gemm_nt_kernel<<<dim3(13, 13), 256, 0, stream>>>(x, Ww, Wall);
  table_kernel<<<400, 256, 0, stream>>>(U, table);
  scan_kernel<<<B_, 512, 0, stream>>>(x, Wall, table, u0, vk, keys, init_state,
                                      alpha_in, state);
  head_kernel<<<B_, 128, 0, stream>>>(queries, emb, q_mult, state, Hw, alpha_q, hbuf);
  out_kernel<<<(V_ + 31) / 32, 256, 0, stream>>>(hbuf, Rw, out);
}

// Round 9
// 545.834 us; speedup vs baseline: 1.1643x; 1.1643x over previous
//
#include <hip/hip_runtime.h>
#include <hip/hip_bf16.h>
#include <cstddef>
#include <cstdint>

#define B_  32
#define S_  50
#define L_  20
#define R_  16
#define D_  100
#define V_  50000
#define T_  320       // L_*R_
#define RD_ 1600      // R_*D_
#define BS_ 1600      // B_*S_
#define NG_ 20        // sign-table groups (5 bits each)
#define NP_ 32        // patterns per group

// ---------------- Phase A: x[bs][j] = sum_l emb0[stories[bs][r*20+l]][d] * in_mult[r*20+l][d]
__global__ __launch_bounds__(512) void x_kernel(
    const int* __restrict__ stories, const float* __restrict__ emb,
    const float* __restrict__ in_mult, float* __restrict__ x)
{
  __shared__ int toks[T_];
  const int bs = blockIdx.x, tid = threadIdx.x;
  const int* st = stories + (size_t)bs * T_;
  if (tid < T_) toks[tid] = st[tid];
  __syncthreads();
  if (tid < 400) {
    const int j4 = tid * 4;
    const int r  = j4 / D_;
    const int d4 = j4 - r * D_;
    float4 acc = make_float4(0.f, 0.f, 0.f, 0.f);
    #pragma unroll
    for (int l = 0; l < 20; ++l) {
      const int t = r * 20 + l;
      const int tok = toks[t];
      if (tok != 0) {
        float4 e = *(const float4*)&emb[(size_t)tok * D_ + d4];
        float4 m = *(const float4*)&in_mult[(size_t)t * D_ + d4];
        acc.x += e.x * m.x; acc.y += e.y * m.y;
        acc.z += e.z * m.z; acc.w += e.w * m.w;
      }
    }
    *(float4*)&x[(size_t)bs * RD_ + j4] = acc;
  }
}

// ---------------- fused prep: sign table (blocks 0..639), vkeys (640..1039), u0 (1040..1439)
// table[g][p][j] = sum_{i<5} (±)U[j][5g+i], p bit i => minus
__global__ __launch_bounds__(256) void prep_kernel(
    const float* __restrict__ U, const float* __restrict__ Vw,
    const float* __restrict__ keys, const float* __restrict__ init_state,
    float* __restrict__ table, float* __restrict__ vk, float* __restrict__ u0)
{
  const int blk = blockIdx.x, tid = threadIdx.x;
  if (blk < NG_ * NP_) {
    const int g = blk >> 5, p = blk & 31;
    float sg[5];
    #pragma unroll
    for (int i = 0; i < 5; ++i) sg[i] = ((p >> i) & 1) ? -1.f : 1.f;
    for (int f = tid; f < 400; f += 256) {
      const int j4 = f * 4;
      float t[4];
      #pragma unroll
      for (int jj = 0; jj < 4; ++jj) {
        const float* ur = &U[(size_t)(j4 + jj) * D_ + 5 * g];
        t[jj] = sg[0]*ur[0] + sg[1]*ur[1] + sg[2]*ur[2] + sg[3]*ur[3] + sg[4]*ur[4];
      }
      *(float4*)&table[((size_t)(g * NP_ + p)) * RD_ + j4] =
          make_float4(t[0], t[1], t[2], t[3]);
    }
  } else if (blk < NG_ * NP_ + 400) {
    const int wave = tid >> 6, lane = tid & 63;
    const int j = (blk - NG_ * NP_) * 4 + wave;
    float acc = 0.f;
    for (int k = lane; k < RD_; k += 64)
      acc += keys[k] * Vw[(size_t)j * RD_ + k];
    #pragma unroll
    for (int off = 32; off > 0; off >>= 1) acc += __shfl_down(acc, off);
    if (lane == 0) vk[j] = acc;
  } else {
    const int wave = tid >> 6, lane = tid & 63;
    const int j = (blk - NG_ * NP_ - 400) * 4 + wave;
    const float* Ur = U + (size_t)j * D_;
    float acc = Ur[lane] * init_state[lane];
    if (lane < 36) acc += Ur[64 + lane] * init_state[64 + lane];
    #pragma unroll
    for (int off = 32; off > 0; off >>= 1) acc += __shfl_down(acc, off);
    if (lane == 0) u0[j] = acc;
  }
}

// ---------------- C[m][n] = sum_k A[m][k]*B[n][k]  (NT fp32, 64x64 tile, 256 thr,
// TM=TN=4, BK=32, LDS double-buffered — proven R6 config)
__global__ __launch_bounds__(256) void gemm_nt_kernel(
    const float* __restrict__ A, const float* __restrict__ B, float* __restrict__ C)
{
  __shared__ __align__(16) float As[2][32][68];
  __shared__ __align__(16) float Bs[2][32][68];
  const int tid = threadIdx.x;
  const int bm = blockIdx.y * 64, bn = blockIdx.x * 64;
  const int tx = tid & 15, ty = tid >> 4;
  const int r = tid >> 2, c = tid & 3;

  const float* Ar = &A[(size_t)(bm + r) * RD_ + c * 8];
  const float* Br = &B[(size_t)(bn + r) * RD_ + c * 8];

  float4 a0 = *(const float4*)Ar,      a1 = *(const float4*)(Ar + 4);
  float4 b0 = *(const float4*)Br,      b1 = *(const float4*)(Br + 4);
  #pragma unroll
  for (int i = 0; i < 4; ++i) {
    As[0][c*8 + i][r]     = (&a0.x)[i];
    As[0][c*8 + 4 + i][r] = (&a1.x)[i];
    Bs[0][c*8 + i][r]     = (&b0.x)[i];
    Bs[0][c*8 + 4 + i][r] = (&b1.x)[i];
  }
  __syncthreads();

  float acc[4][4] = {};
  for (int t = 0; t < 50; ++t) {
    const int cur = t & 1;
    if (t < 49) {
      const float* An = Ar + (t + 1) * 32;
      const float* Bn = Br + (t + 1) * 32;
      a0 = *(const float4*)An; a1 = *(const float4*)(An + 4);
      b0 = *(const float4*)Bn; b1 = *(const float4*)(Bn + 4);
    }
    #pragma unroll
    for (int k = 0; k < 32; ++k) {
      float4 av = *(const float4*)&As[cur][k][ty * 4];
      float4 bv = *(const float4*)&Bs[cur][k][tx * 4];
      acc[0][0] += av.x*bv.x; acc[0][1] += av.x*bv.y; acc[0][2] += av.x*bv.z; acc[0][3] += av.x*bv.w;
      acc[1][0] += av.y*bv.x; acc[1][1] += av.y*bv.y; acc[1][2] += av.y*bv.z; acc[1][3] += av.y*bv.w;
      acc[2][0] += av.z*bv.x; acc[2][1] += av.z*bv.y; acc[2][2] += av.z*bv.z; acc[2][3] += av.z*bv.w;
      acc[3][0] += av.w*bv.x; acc[3][1] += av.w*bv.y; acc[3][2] += av.w*bv.z; acc[3][3] += av.w*bv.w;
    }
    if (t < 49) {
      const int nxt = cur ^ 1;
      #pragma unroll
      for (int i = 0; i < 4; ++i) {
        As[nxt][c*8 + i][r]     = (&a0.x)[i];
        As[nxt][c*8 + 4 + i][r] = (&a1.x)[i];
        Bs[nxt][c*8 + i][r]     = (&b0.x)[i];
        Bs[nxt][c*8 + 4 + i][r] = (&b1.x)[i];
      }
    }
    __syncthreads();
  }
  #pragma unroll
  for (int i = 0; i < 4; ++i) {
    *(float4*)&C[(size_t)(bm + ty*4 + i) * RD_ + bn + tx*4] =
        make_float4(acc[i][0], acc[i][1], acc[i][2], acc[i][3]);
  }
}

// ---------------- scan + fused head: one block per b.
// Step 0 via precomputed u0; steps>=1 via 5-bit sign table (20 loads/thread).
__global__ __launch_bounds__(512, 2) void scan_kernel(
    const float* __restrict__ x,       // [BS_][RD_]
    const float* __restrict__ Wall,    // [BS_][RD_]
    const float* __restrict__ table,   // [NG_*NP_][RD_]
    const float* __restrict__ u0,      // [RD_]
    const float* __restrict__ vkeys,   // [RD_]
    const float* __restrict__ keys,    // [RD_]
    const float* __restrict__ init_state, // [D_]
    const float* __restrict__ alpha_in_p,
    const int*   __restrict__ queries, // [B_][L_]
    const float* __restrict__ emb,     // [V_][D_]
    const float* __restrict__ q_mult,  // [L_][D_]
    const float* __restrict__ Hw,      // [D_][D_]
    const float* __restrict__ alpha_q_p,
    float* __restrict__ h_g)           // [B_][D_]
{
  const int b = blockIdx.x, tid = threadIdx.x;
  __shared__ __align__(16) float s_state[D_];
  __shared__ __align__(16) float s_c[RD_];
  __shared__ float s_hw[D_ * 101];     // Hw padded stride 101 (conflict-free)
  __shared__ unsigned long long s_mask[2];
  const float alpha = alpha_in_p[0];
  const bool active = (tid < 400);
  const int j4 = tid * 4;
  const int d4 = (j4 % D_);
  float4 kk = make_float4(0.f,0.f,0.f,0.f), vv = kk;
  const float* xb = x    + (size_t)b * S_ * RD_;
  const float* wb = Wall + (size_t)b * S_ * RD_;
  float4 bx[5], bw[5];
  #pragma unroll
  for (int i = 0; i < 5; ++i) { bx[i] = make_float4(0.f,0.f,0.f,0.f); bw[i] = bx[i]; }
  if (active) {
    kk = *(const float4*)&keys[j4];
    vv = *(const float4*)&vkeys[j4];
    #pragma unroll
    for (int i = 0; i < 5; ++i) {          // preload steps 0..4
      bx[i] = *(const float4*)&xb[(size_t)i * RD_ + j4];
      bw[i] = *(const float4*)&wb[(size_t)i * RD_ + j4];
    }
  }
  if (tid < D_) s_state[tid] = init_state[tid];
  __syncthreads();

  for (int sg = 0; sg < S_; sg += 5) {
    #pragma unroll
    for (int i = 0; i < 5; ++i) {
      const int s = sg + i;
      if (active) {
        const float4 sent = bx[i], w = bw[i];
        if (s + 5 < S_) {                  // stagger: prefetch step s+5
          bx[i] = *(const float4*)&xb[(size_t)(s + 5) * RD_ + j4];
          bw[i] = *(const float4*)&wb[(size_t)(s + 5) * RD_ + j4];
        }
        float4 u;
        if (s == 0) {
          u = *(const float4*)&u0[j4];
        } else {
          u = make_float4(0.f,0.f,0.f,0.f);
          const unsigned long long m0 = s_mask[0];
          const unsigned long long m1 = s_mask[1];
          #pragma unroll
          for (int g = 0; g < NG_; ++g) {
            unsigned idx;
            if (g < 12)       idx = (unsigned)((m0 >> (5 * g)) & 31ull);
            else if (g == 12) idx = (unsigned)(((m0 >> 60) | (m1 << 4)) & 31ull);
            else              idx = (unsigned)((m1 >> (5 * g - 64)) & 31ull);
            float4 tv = *(const float4*)&table[((size_t)(g * NP_) + idx) * RD_ + j4];
            u.x += tv.x; u.y += tv.y; u.z += tv.z; u.w += tv.w;
          }
        }
        float4 sd = *(const float4*)&s_state[d4];
        float zx = sent.x * sd.x + sent.x * kk.x;
        float zy = sent.y * sd.y + sent.y * kk.y;
        float zz = sent.z * sd.z + sent.z * kk.z;
        float zw = sent.w * sd.w + sent.w * kk.w;
        float gx = 1.0f / (1.0f + expf(-zx));
        float gy = 1.0f / (1.0f + expf(-zy));
        float gz = 1.0f / (1.0f + expf(-zz));
        float gw = 1.0f / (1.0f + expf(-zw));
        float cx = u.x + vv.x + w.x; cx = cx >= 0.f ? cx : alpha * cx;
        float cy = u.y + vv.y + w.y; cy = cy >= 0.f ? cy : alpha * cy;
        float cz = u.z + vv.z + w.z; cz = cz >= 0.f ? cz : alpha * cz;
        float cw = u.w + vv.w + w.w; cw = cw >= 0.f ? cw : alpha * cw;
        float4 cc;
        cc.x = (gx == 0.5f) ? 0.f : cx * gx;
        cc.y = (gy == 0.5f) ? 0.f : cy * gy;
        cc.z = (gz == 0.5f) ? 0.f : cz * gz;
        cc.w = (gw == 0.5f) ? 0.f : cw * gw;
        *(float4*)&s_c[j4] = cc;
      }
      __syncthreads();
      if (tid < D_) {
        float csum = 0.f;
        #pragma unroll
        for (int r = 0; r < R_; ++r) csum += s_c[r * D_ + tid];
        float v = s_state[tid] + csum;
        v = v / sqrtf(v * v);   // faithful: torch.norm over singleton dim -> sign
        s_state[tid] = v;
        unsigned long long mask = __ballot(v < 0.f);
        if ((tid & 63) == 0) s_mask[tid >> 6] = mask;
      }
      __syncthreads();
    }
  }

  // ---- fused head: h[b][d] = prelu(q[b][d] + dot(state, Hw[d]), alpha_q)
  for (int f = tid; f < D_ * D_; f += 512) {
    const int row = f / D_, col = f - row * D_;
    s_hw[row * 101 + col] = Hw[f];
  }
  __syncthreads();
  if (tid < D_) {
    float q = 0.f;
    #pragma unroll
    for (int l = 0; l < L_; ++l) {
      const int tok = queries[b * L_ + l];
      if (tok != 0) q += emb[(size_t)tok * D_ + tid] * q_mult[l * D_ + tid];
    }
    float a = 0.f;
    #pragma unroll 4
    for (int k = 0; k < D_; ++k) a += s_state[k] * s_hw[tid * 101 + k];
    float h = q + a;
    const float aq = alpha_q_p[0];
    h = h >= 0.f ? h : aq * h;
    h_g[(size_t)b * D_ + tid] = h;
  }
}

// ---------------- out[b][v] = sum_k h[b][k] * Rw[v][k]   (v-tile=32 staged in LDS)
__global__ __launch_bounds__(256) void out_kernel(
    const float* __restrict__ h_g, const float* __restrict__ Rw, float* __restrict__ out)
{
  __shared__ __align__(16) float sh[B_ * D_];    // 3200
  __shared__ __align__(16) float sr[32 * D_];    // 3200
  int tid = threadIdx.x;
  int v0 = blockIdx.x * 32;
  for (int i = tid; i < B_ * D_; i += 256) sh[i] = h_g[i];
  int nrows = V_ - v0; if (nrows > 32) nrows = 32;
  for (int i = tid; i < nrows * D_; i += 256) sr[i] = Rw[(size_t)v0 * D_ + i];
  __syncthreads();
  const float4* sh4 = (const float4*)sh;
  const float4* sr4 = (const float4*)sr;
  int tv = (tid & 15) * 2;
  int tb = (tid >> 4) * 2;
  float a00 = 0.f, a01 = 0.f, a10 = 0.f, a11 = 0.f;
  #pragma unroll
  for (int kc = 0; kc < 25; ++kc) {
    float4 h0 = sh4[tb * 25 + kc];
    float4 h1 = sh4[(tb + 1) * 25 + kc];
    float4 r0 = sr4[tv * 25 + kc];
    float4 r1 = sr4[(tv + 1) * 25 + kc];
    a00 += h0.x*r0.x + h0.y*r0.y + h0.z*r0.z + h0.w*r0.w;
    a01 += h0.x*r1.x + h0.y*r1.y + h0.z*r1.z + h0.w*r1.w;
    a10 += h1.x*r0.x + h1.y*r0.y + h1.z*r0.z + h1.w*r0.w;
    a11 += h1.x*r1.x + h1.y*r1.y + h1.z*r1.z + h1.w*r1.w;
  }
  if (tv < nrows) {
    out[(size_t)tb * V_ + v0 + tv] = a00;
    out[(size_t)(tb + 1) * V_ + v0 + tv] = a10;
  }
  if (tv + 1 < nrows) {
    out[(size_t)tb * V_ + v0 + tv + 1] = a01;
    out[(size_t)(tb + 1) * V_ + v0 + tv + 1] = a11;
  }
}

extern "C" void kernel_launch(void* const* d_in, const int* in_sizes, int n_in,
                              void* d_out, int out_size, void* d_ws, size_t ws_size,
                              hipStream_t stream) {
  const int*   stories    = (const int*)  d_in[0];
  const int*   queries    = (const int*)  d_in[1];
  const float* emb        = (const float*)d_in[2];
  const float* in_mult    = (const float*)d_in[3];
  const float* q_mult     = (const float*)d_in[4];
  const float* keys       = (const float*)d_in[5];
  const float* init_state = (const float*)d_in[6];
  const float* U          = (const float*)d_in[7];
  const float* Vw         = (const float*)d_in[8];
  const float* Ww         = (const float*)d_in[9];
  const float* Hw         = (const float*)d_in[10];
  const float* Rw         = (const float*)d_in[11];
  const float* alpha_in   = (const float*)d_in[12];
  const float* alpha_q    = (const float*)d_in[13];
  float* out = (float*)d_out;

  char* ws = (char*)d_ws;
  float* x     = (float*)(ws);               // 10,240,000 B
  float* Wall  = (float*)(ws + 10240000);    // 10,240,000 B
  float* table = (float*)(ws + 20480000);    //  4,096,000 B (20*32*1600*4)
  float* vk    = (float*)(ws + 24576000);    //      6,400 B
  float* u0    = (float*)(ws + 24582400);    //      6,400 B
  float* hbuf  = (float*)(ws + 24588800);    //     12,800 B
  // total 24,601,600 B

  x_kernel<<<BS_, 512, 0, stream>>>(stories, emb, in_mult, x);
  prep_kernel<<<NG_ * NP_ + 800, 256, 0, stream>>>(U, Vw, keys, init_state,
                                                   table, vk, u0);
  gemm_nt_kernel<<<dim3(25, 25), 256, 0, stream>>>(x, Ww, Wall);
  scan_kernel<<<B_, 512, 0, stream>>>(x, Wall, table, u0, vk, keys, init_state,
                                      alpha_in, queries, emb, q_mult, Hw, alpha_q,
                                      hbuf);
  out_kernel<<<(V_ + 31) / 32, 256, 0, stream>>>(hbuf, Rw, out);
}

// Round 10
// 457.040 us; speedup vs baseline: 1.3906x; 1.1943x over previous
//
#include <hip/hip_runtime.h>
#include <hip/hip_bf16.h>
#include <cstddef>
#include <cstdint>

#define B_  32
#define S_  50
#define L_  20
#define R_  16
#define D_  100
#define V_  50000
#define T_  320       // L_*R_
#define RD_ 1600      // R_*D_
#define BS_ 1600      // B_*S_
#define NG_ 25        // sign-table groups (4 bits each)
#define NP_ 16        // patterns per group

typedef float v4f __attribute__((ext_vector_type(4)));
#define NTL(p) __builtin_nontemporal_load((const v4f*)(p))

// ---------------- fused setup:
// blocks [0,1600): x[bs][j] = sum_l emb0[stories]*in_mult   (512 thr)
// blocks [1600,2000): sign table from U (4-bit)             (400 thr used)
// blocks [2000,2200): vkeys (8 waves -> 8 j's per block)
// blocks [2200,2400): u0 = U @ init_state
__global__ __launch_bounds__(512) void setup_kernel(
    const int* __restrict__ stories, const float* __restrict__ emb,
    const float* __restrict__ in_mult, const float* __restrict__ U,
    const float* __restrict__ Vw, const float* __restrict__ keys,
    const float* __restrict__ init_state,
    float* __restrict__ x, float* __restrict__ table,
    float* __restrict__ vk, float* __restrict__ u0)
{
  const int blk = blockIdx.x, tid = threadIdx.x;
  if (blk < 1600) {
    __shared__ int toks[T_];
    const int* st = stories + (size_t)blk * T_;
    if (tid < T_) toks[tid] = st[tid];
    __syncthreads();
    if (tid < 400) {
      const int j4 = tid * 4;
      const int r  = j4 / D_;
      const int d4 = j4 - r * D_;
      float4 acc = make_float4(0.f, 0.f, 0.f, 0.f);
      #pragma unroll
      for (int l = 0; l < 20; ++l) {
        const int t = r * 20 + l;
        const int tok = toks[t];
        if (tok != 0) {
          float4 e = *(const float4*)&emb[(size_t)tok * D_ + d4];
          float4 m = *(const float4*)&in_mult[(size_t)t * D_ + d4];
          acc.x += e.x * m.x; acc.y += e.y * m.y;
          acc.z += e.z * m.z; acc.w += e.w * m.w;
        }
      }
      *(float4*)&x[(size_t)blk * RD_ + j4] = acc;
    }
  } else if (blk < 2000) {
    const int q = blk - 1600;
    const int g = q >> 4, p = q & 15;
    const float s0 = (p & 1) ? -1.f : 1.f;
    const float s1 = (p & 2) ? -1.f : 1.f;
    const float s2 = (p & 4) ? -1.f : 1.f;
    const float s3 = (p & 8) ? -1.f : 1.f;
    if (tid < 400) {
      const int j4 = tid * 4;
      float t[4];
      #pragma unroll
      for (int jj = 0; jj < 4; ++jj) {
        const float* ur = &U[(size_t)(j4 + jj) * D_ + 4 * g];
        t[jj] = s0*ur[0] + s1*ur[1] + s2*ur[2] + s3*ur[3];
      }
      *(float4*)&table[((size_t)(g * NP_ + p)) * RD_ + j4] =
          make_float4(t[0], t[1], t[2], t[3]);
    }
  } else if (blk < 2200) {
    const int wave = tid >> 6, lane = tid & 63;
    const int j = (blk - 2000) * 8 + wave;
    float acc = 0.f;
    for (int k = lane; k < RD_; k += 64)
      acc += keys[k] * Vw[(size_t)j * RD_ + k];
    #pragma unroll
    for (int off = 32; off > 0; off >>= 1) acc += __shfl_down(acc, off);
    if (lane == 0) vk[j] = acc;
  } else {
    const int wave = tid >> 6, lane = tid & 63;
    const int j = (blk - 2200) * 8 + wave;
    const float* Ur = U + (size_t)j * D_;
    float acc = Ur[lane] * init_state[lane];
    if (lane < 36) acc += Ur[64 + lane] * init_state[64 + lane];
    #pragma unroll
    for (int off = 32; off > 0; off >>= 1) acc += __shfl_down(acc, off);
    if (lane == 0) u0[j] = acc;
  }
}

// ---------------- split-K NT fp32 GEMM: C_z[m][n] = sum_{k in half z} A[m][k]*B[n][k]
// 64x64 tile, 256 thr, TM=TN=4, BK=32, LDS dbuf; grid (25,25,2) = 1250 blocks.
__global__ __launch_bounds__(256) void gemm_nt_kernel(
    const float* __restrict__ A, const float* __restrict__ B,
    float* __restrict__ C0, float* __restrict__ C1)
{
  __shared__ __align__(16) float As[2][32][68];
  __shared__ __align__(16) float Bs[2][32][68];
  const int tid = threadIdx.x;
  const int bm = blockIdx.y * 64, bn = blockIdx.x * 64;
  const int z = blockIdx.z;
  const int tx = tid & 15, ty = tid >> 4;
  const int r = tid >> 2, c = tid & 3;

  const float* Ar = &A[(size_t)(bm + r) * RD_ + z * 800 + c * 8];
  const float* Br = &B[(size_t)(bn + r) * RD_ + z * 800 + c * 8];

  float4 a0 = *(const float4*)Ar,      a1 = *(const float4*)(Ar + 4);
  float4 b0 = *(const float4*)Br,      b1 = *(const float4*)(Br + 4);
  #pragma unroll
  for (int i = 0; i < 4; ++i) {
    As[0][c*8 + i][r]     = (&a0.x)[i];
    As[0][c*8 + 4 + i][r] = (&a1.x)[i];
    Bs[0][c*8 + i][r]     = (&b0.x)[i];
    Bs[0][c*8 + 4 + i][r] = (&b1.x)[i];
  }
  __syncthreads();

  float acc[4][4] = {};
  for (int t = 0; t < 25; ++t) {
    const int cur = t & 1;
    if (t < 24) {
      const float* An = Ar + (t + 1) * 32;
      const float* Bn = Br + (t + 1) * 32;
      a0 = *(const float4*)An; a1 = *(const float4*)(An + 4);
      b0 = *(const float4*)Bn; b1 = *(const float4*)(Bn + 4);
    }
    #pragma unroll
    for (int k = 0; k < 32; ++k) {
      float4 av = *(const float4*)&As[cur][k][ty * 4];
      float4 bv = *(const float4*)&Bs[cur][k][tx * 4];
      acc[0][0] += av.x*bv.x; acc[0][1] += av.x*bv.y; acc[0][2] += av.x*bv.z; acc[0][3] += av.x*bv.w;
      acc[1][0] += av.y*bv.x; acc[1][1] += av.y*bv.y; acc[1][2] += av.y*bv.z; acc[1][3] += av.y*bv.w;
      acc[2][0] += av.z*bv.x; acc[2][1] += av.z*bv.y; acc[2][2] += av.z*bv.z; acc[2][3] += av.z*bv.w;
      acc[3][0] += av.w*bv.x; acc[3][1] += av.w*bv.y; acc[3][2] += av.w*bv.z; acc[3][3] += av.w*bv.w;
    }
    if (t < 24) {
      const int nxt = cur ^ 1;
      #pragma unroll
      for (int i = 0; i < 4; ++i) {
        As[nxt][c*8 + i][r]     = (&a0.x)[i];
        As[nxt][c*8 + 4 + i][r] = (&a1.x)[i];
        Bs[nxt][c*8 + i][r]     = (&b0.x)[i];
        Bs[nxt][c*8 + 4 + i][r] = (&b1.x)[i];
      }
    }
    __syncthreads();
  }
  float* Cz = z ? C1 : C0;
  #pragma unroll
  for (int i = 0; i < 4; ++i) {
    *(float4*)&Cz[(size_t)(bm + ty*4 + i) * RD_ + bn + tx*4] =
        make_float4(acc[i][0], acc[i][1], acc[i][2], acc[i][3]);
  }
}

// ---------------- Wall += Wh1   (in-place add of the second K-half)
__global__ __launch_bounds__(256) void add_kernel(
    float* __restrict__ Wall, const float* __restrict__ Wh1)
{
  const int i = (blockIdx.x * 256 + threadIdx.x) * 4;
  float4 a = *(const float4*)&Wall[i];
  float4 b = *(const float4*)&Wh1[i];
  *(float4*)&Wall[i] = make_float4(a.x + b.x, a.y + b.y, a.z + b.z, a.w + b.w);
}

// ---------------- scan + fused head: one block per b.
// Step 0 via precomputed u0; steps>=1 via 4-bit sign table (25 loads/thread).
// x/Wall loads non-temporal (protect table L2 residency); 5-deep stagger prefetch.
__global__ __launch_bounds__(512, 2) void scan_kernel(
    const float* __restrict__ x,       // [BS_][RD_]
    const float* __restrict__ Wall,    // [BS_][RD_]
    const float* __restrict__ table,   // [NG_*NP_][RD_]
    const float* __restrict__ u0,      // [RD_]
    const float* __restrict__ vkeys,   // [RD_]
    const float* __restrict__ keys,    // [RD_]
    const float* __restrict__ init_state, // [D_]
    const float* __restrict__ alpha_in_p,
    const int*   __restrict__ queries, // [B_][L_]
    const float* __restrict__ emb,     // [V_][D_]
    const float* __restrict__ q_mult,  // [L_][D_]
    const float* __restrict__ Hw,      // [D_][D_]
    const float* __restrict__ alpha_q_p,
    float* __restrict__ h_g)           // [B_][D_]
{
  const int b = blockIdx.x, tid = threadIdx.x;
  __shared__ __align__(16) float s_state[D_];
  __shared__ __align__(16) float s_c[RD_];
  __shared__ float s_hw[D_ * 101];     // Hw padded stride 101 (conflict-free)
  __shared__ unsigned long long s_mask[2];
  const float alpha = alpha_in_p[0];
  const bool active = (tid < 400);
  const int j4 = tid * 4;
  const int d4 = (j4 % D_);
  float4 kk = make_float4(0.f,0.f,0.f,0.f), vv = kk;
  const float* xb = x    + (size_t)b * S_ * RD_;
  const float* wb = Wall + (size_t)b * S_ * RD_;
  v4f bx[5], bw[5];
  #pragma unroll
  for (int i = 0; i < 5; ++i) { bx[i] = (v4f)(0.f); bw[i] = (v4f)(0.f); }
  if (active) {
    kk = *(const float4*)&keys[j4];
    vv = *(const float4*)&vkeys[j4];
    #pragma unroll
    for (int i = 0; i < 5; ++i) {          // preload steps 0..4 (non-temporal)
      bx[i] = NTL(&xb[(size_t)i * RD_ + j4]);
      bw[i] = NTL(&wb[(size_t)i * RD_ + j4]);
    }
  }
  if (tid < D_) s_state[tid] = init_state[tid];
  __syncthreads();

  for (int sg = 0; sg < S_; sg += 5) {
    #pragma unroll
    for (int i = 0; i < 5; ++i) {
      const int s = sg + i;
      if (active) {
        const v4f sent = bx[i], w = bw[i];
        if (s + 5 < S_) {                  // stagger: prefetch step s+5
          bx[i] = NTL(&xb[(size_t)(s + 5) * RD_ + j4]);
          bw[i] = NTL(&wb[(size_t)(s + 5) * RD_ + j4]);
        }
        v4f u;
        if (s == 0) {
          float4 t0 = *(const float4*)&u0[j4];
          u.x = t0.x; u.y = t0.y; u.z = t0.z; u.w = t0.w;
        } else {
          u = (v4f)(0.f);
          const unsigned long long m0 = s_mask[0];
          const unsigned long long m1 = s_mask[1];
          #pragma unroll
          for (int g = 0; g < NG_; ++g) {
            const unsigned idx = (g < 16)
                ? (unsigned)((m0 >> (4 * g)) & 15ull)
                : (unsigned)((m1 >> (4 * g - 64)) & 15ull);
            float4 tv = *(const float4*)&table[((size_t)(g * NP_) + idx) * RD_ + j4];
            u.x += tv.x; u.y += tv.y; u.z += tv.z; u.w += tv.w;
          }
        }
        float4 sd = *(const float4*)&s_state[d4];
        float zx = sent.x * sd.x + sent.x * kk.x;
        float zy = sent.y * sd.y + sent.y * kk.y;
        float zz = sent.z * sd.z + sent.z * kk.z;
        float zw = sent.w * sd.w + sent.w * kk.w;
        float gx = 1.0f / (1.0f + expf(-zx));
        float gy = 1.0f / (1.0f + expf(-zy));
        float gz = 1.0f / (1.0f + expf(-zz));
        float gw = 1.0f / (1.0f + expf(-zw));
        float cx = u.x + vv.x + w.x; cx = cx >= 0.f ? cx : alpha * cx;
        float cy = u.y + vv.y + w.y; cy = cy >= 0.f ? cy : alpha * cy;
        float cz = u.z + vv.z + w.z; cz = cz >= 0.f ? cz : alpha * cz;
        float cw = u.w + vv.w + w.w; cw = cw >= 0.f ? cw : alpha * cw;
        v4f cc;
        cc.x = (gx == 0.5f) ? 0.f : cx * gx;
        cc.y = (gy == 0.5f) ? 0.f : cy * gy;
        cc.z = (gz == 0.5f) ? 0.f : cz * gz;
        cc.w = (gw == 0.5f) ? 0.f : cw * gw;
        *(v4f*)&s_c[j4] = cc;
      }
      __syncthreads();
      if (tid < D_) {
        float csum = 0.f;
        #pragma unroll
        for (int r = 0; r < R_; ++r) csum += s_c[r * D_ + tid];
        float v = s_state[tid] + csum;
        v = v / sqrtf(v * v);   // faithful: torch.norm over singleton dim -> sign
        s_state[tid] = v;
        unsigned long long mask = __ballot(v < 0.f);
        if ((tid & 63) == 0) s_mask[tid >> 6] = mask;
      }
      __syncthreads();
    }
  }

  // ---- fused head: h[b][d] = prelu(q[b][d] + dot(state, Hw[d]), alpha_q)
  for (int f = tid; f < D_ * D_; f += 512) {
    const int row = f / D_, col = f - row * D_;
    s_hw[row * 101 + col] = Hw[f];
  }
  __syncthreads();
  if (tid < D_) {
    float q = 0.f;
    #pragma unroll
    for (int l = 0; l < L_; ++l) {
      const int tok = queries[b * L_ + l];
      if (tok != 0) q += emb[(size_t)tok * D_ + tid] * q_mult[l * D_ + tid];
    }
    float a = 0.f;
    #pragma unroll 4
    for (int k = 0; k < D_; ++k) a += s_state[k] * s_hw[tid * 101 + k];
    float h = q + a;
    const float aq = alpha_q_p[0];
    h = h >= 0.f ? h : aq * h;
    h_g[(size_t)b * D_ + tid] = h;
  }
}

// ---------------- out[b][v] = sum_k h[b][k] * Rw[v][k]   (v-tile=32 staged in LDS)
__global__ __launch_bounds__(256) void out_kernel(
    const float* __restrict__ h_g, const float* __restrict__ Rw, float* __restrict__ out)
{
  __shared__ __align__(16) float sh[B_ * D_];    // 3200
  __shared__ __align__(16) float sr[32 * D_];    // 3200
  int tid = threadIdx.x;
  int v0 = blockIdx.x * 32;
  for (int i = tid; i < B_ * D_; i += 256) sh[i] = h_g[i];
  int nrows = V_ - v0; if (nrows > 32) nrows = 32;
  for (int i = tid; i < nrows * D_; i += 256) sr[i] = Rw[(size_t)v0 * D_ + i];
  __syncthreads();
  const float4* sh4 = (const float4*)sh;
  const float4* sr4 = (const float4*)sr;
  int tv = (tid & 15) * 2;
  int tb = (tid >> 4) * 2;
  float a00 = 0.f, a01 = 0.f, a10 = 0.f, a11 = 0.f;
  #pragma unroll
  for (int kc = 0; kc < 25; ++kc) {
    float4 h0 = sh4[tb * 25 + kc];
    float4 h1 = sh4[(tb + 1) * 25 + kc];
    float4 r0 = sr4[tv * 25 + kc];
    float4 r1 = sr4[(tv + 1) * 25 + kc];
    a00 += h0.x*r0.x + h0.y*r0.y + h0.z*r0.z + h0.w*r0.w;
    a01 += h0.x*r1.x + h0.y*r1.y + h0.z*r1.z + h0.w*r1.w;
    a10 += h1.x*r0.x + h1.y*r0.y + h1.z*r0.z + h1.w*r0.w;
    a11 += h1.x*r1.x + h1.y*r1.y + h1.z*r1.z + h1.w*r1.w;
  }
  if (tv < nrows) {
    out[(size_t)tb * V_ + v0 + tv] = a00;
    out[(size_t)(tb + 1) * V_ + v0 + tv] = a10;
  }
  if (tv + 1 < nrows) {
    out[(size_t)tb * V_ + v0 + tv + 1] = a01;
    out[(size_t)(tb + 1) * V_ + v0 + tv + 1] = a11;
  }
}

extern "C" void kernel_launch(void* const* d_in, const int* in_sizes, int n_in,
                              void* d_out, int out_size, void* d_ws, size_t ws_size,
                              hipStream_t stream) {
  const int*   stories    = (const int*)  d_in[0];
  const int*   queries    = (const int*)  d_in[1];
  const float* emb        = (const float*)d_in[2];
  const float* in_mult    = (const float*)d_in[3];
  const float* q_mult     = (const float*)d_in[4];
  const float* keys       = (const float*)d_in[5];
  const float* init_state = (const float*)d_in[6];
  const float* U          = (const float*)d_in[7];
  const float* Vw         = (const float*)d_in[8];
  const float* Ww         = (const float*)d_in[9];
  const float* Hw         = (const float*)d_in[10];
  const float* Rw         = (const float*)d_in[11];
  const float* alpha_in   = (const float*)d_in[12];
  const float* alpha_q    = (const float*)d_in[13];
  float* out = (float*)d_out;

  char* ws = (char*)d_ws;
  float* x     = (float*)(ws);               // 10,240,000 B
  float* Wall  = (float*)(ws + 10240000);    // 10,240,000 B
  float* Wh1   = (float*)(ws + 20480000);    // 10,240,000 B
  float* table = (float*)(ws + 30720000);    //  2,560,000 B (25*16*1600*4)
  float* vk    = (float*)(ws + 33280000);    //      6,400 B
  float* u0    = (float*)(ws + 33286400);    //      6,400 B
  float* hbuf  = (float*)(ws + 33292800);    //     12,800 B
  // total 33,305,600 B

  setup_kernel<<<2400, 512, 0, stream>>>(stories, emb, in_mult, U, Vw, keys,
                                         init_state, x, table, vk, u0);
  gemm_nt_kernel<<<dim3(25, 25, 2), 256, 0, stream>>>(x, Ww, Wall, Wh1);
  add_kernel<<<BS_ * RD_ / 1024, 256, 0, stream>>>(Wall, Wh1);
  scan_kernel<<<B_, 512, 0, stream>>>(x, Wall, table, u0, vk, keys, init_state,
                                      alpha_in, queries, emb, q_mult, Hw, alpha_q,
                                      hbuf);
  out_kernel<<<(V_ + 31) / 32, 256, 0, stream>>>(hbuf, Rw, out);
}